// Round 1
// baseline (18.654 us; speedup 1.0000x reference)
//
#include <hip/hip_runtime.h>
#include <math.h>

constexpr int B_ = 4, L_ = 2048, K_ = 64, T_ = 1000;
#define EPSF 1e-6f

__device__ __forceinline__ float wave_max64(float v) {
#pragma unroll
    for (int o = 32; o; o >>= 1) v = fmaxf(v, __shfl_xor(v, o, 64));
    return v;
}

__device__ __forceinline__ float wave_sum64(float v) {
#pragma unroll
    for (int o = 32; o; o >>= 1) v += __shfl_xor(v, o, 64);
    return v;
}

__device__ __forceinline__ float logaddexpf_(float a, float b) {
    float m = fmaxf(a, b);
    return m + log1pf(expf(fminf(a, b) - m));
}

// log((1-w)*exp(a) + w*exp(b)) with boundary handling; w is wave-uniform.
__device__ __forceinline__ float mix_logits(float a, float b, float w) {
    if (w < 1e-6f) return a;
    if (w > 1.0f - 1e-6f) return b;
    float ws = fminf(fmaxf(w, 1e-6f), 1.0f - 1e-6f);
    return logaddexpf_(a + logf(1.0f - ws), b + logf(ws));
}

// Returns this lane's softmax probability u[lane] of the mixed marginal logits
// for time step tt (a wave-uniform scalar), class embedding row value `we`.
__device__ __forceinline__ float get_u(int lane, float we,
                                       const float* __restrict__ W_t,
                                       int tt, int x0) {
    float raw = we + W_t[tt * K_ + lane];
    // log_softmax(raw)
    float mx = wave_max64(raw);
    float ssum = wave_sum64(expf(raw - mx));
    float log_net = raw - mx - logf(ssum);

    float tn = (float)tt / (float)T_;          // t_norm
    float cr = 2.0f * tn - 1.0f;               // control_ratio = (2*tn-1)^2
    cr *= cr;

    float x0lp = (lane == x0) ? logf(1.0f + EPSF) : logf(EPSF);
    const float uniflp = logf(1.0f / (float)K_);

    float control = mix_logits(x0lp, uniflp, tn);
    float logit = mix_logits(log_net, control, cr);

    // softmax(logit)
    float m2 = wave_max64(logit);
    float e = expf(logit - m2);
    float s2 = wave_sum64(e);
    return e / s2;
}

__global__ __launch_bounds__(256) void fldd_kernel(
        const float* __restrict__ W_emb,
        const float* __restrict__ W_t,
        const int* __restrict__ x_0,
        const int* __restrict__ x_t,
        const int* __restrict__ t,
        float* __restrict__ out) {
    const int tid = threadIdx.x;
    const int lane = tid & 63;
    const int p = blockIdx.x * 4 + (tid >> 6);   // position in [0, B*L)
    if (p >= B_ * L_) return;
    const int b = p >> 11;                        // p / L_  (L_ = 2048)

    const int x0 = x_0[p];
    const int xt = x_t[p];
    const int tb = t[b];

    const float we = W_emb[x0 * K_ + lane];

    const float u_t = get_u(lane, we, W_t, tb, x0);
    const float u_s = get_u(lane, we, W_t, tb - 1, x0);

    // coupling row j = xt, column k = lane
    const float diff = fmaxf(u_s - u_t, 0.0f);
    const float D = wave_sum64(diff);
    const float m_st = diff / (D + EPSF);
    const float S = D / (D + EPSF);               // sum_k m_st

    const float usj = __shfl(u_s, xt, 64);
    const float utj = __shfl(u_t, xt, 64);
    const float prob_stay = fminf(usj, utj) / (utj + EPSF);
    const float prob_move = fmaxf(utj - usj, 0.0f) / (utj + EPSF);

    const float q = ((lane == xt) ? prob_stay : 0.0f) + prob_move * m_st;
    const float denom = prob_stay + prob_move * S + EPSF;
    const float post = q / denom;

    out[p * K_ + lane] = logf(post + EPSF);
}

extern "C" void kernel_launch(void* const* d_in, const int* in_sizes, int n_in,
                              void* d_out, int out_size, void* d_ws, size_t ws_size,
                              hipStream_t stream) {
    const float* W_emb = (const float*)d_in[0];
    const float* W_t   = (const float*)d_in[1];
    const int*   x_0   = (const int*)d_in[2];
    const int*   x_t   = (const int*)d_in[3];
    const int*   t     = (const int*)d_in[4];
    float* out = (float*)d_out;

    const int positions = B_ * L_;                // 8192
    const int blocks = positions / 4;             // 4 waves (positions) per block
    fldd_kernel<<<blocks, 256, 0, stream>>>(W_emb, W_t, x_0, x_t, t, out);
}

// Round 2
// 12.580 us; speedup vs baseline: 1.4827x; 1.4827x over previous
//
#include <hip/hip_runtime.h>
#include <math.h>

constexpr int B_ = 4, L_ = 2048, K_ = 64, T_ = 1000;
#define EPSF 1e-6f

__device__ __forceinline__ float wave_max64(float v) {
#pragma unroll
    for (int o = 32; o; o >>= 1) v = fmaxf(v, __shfl_xor(v, o, 64));
    return v;
}

__device__ __forceinline__ float wave_sum64(float v) {
#pragma unroll
    for (int o = 32; o; o >>= 1) v += __shfl_xor(v, o, 64);
    return v;
}

__device__ __forceinline__ float logaddexpf_(float a, float b) {
    float m = fmaxf(a, b);
    return m + log1pf(expf(fminf(a, b) - m));
}

// log((1-w)*exp(a) + w*exp(b)) with boundary handling; w is wave-uniform.
__device__ __forceinline__ float mix_logits(float a, float b, float w) {
    if (w < 1e-6f) return a;
    if (w > 1.0f - 1e-6f) return b;
    float ws = fminf(fmaxf(w, 1e-6f), 1.0f - 1e-6f);
    return logaddexpf_(a + logf(1.0f - ws), b + logf(ws));
}

// This lane's softmax probability u[lane] of the mixed marginal logits for
// time step tt (wave-uniform), class embedding row value `we`.
__device__ __forceinline__ float get_u(int lane, float we,
                                       const float* __restrict__ W_t,
                                       int tt, int x0) {
    float raw = we + W_t[tt * K_ + lane];
    float mx = wave_max64(raw);
    float ssum = wave_sum64(expf(raw - mx));
    float log_net = raw - mx - logf(ssum);

    float tn = (float)tt / (float)T_;
    float cr = 2.0f * tn - 1.0f;
    cr *= cr;

    float x0lp = (lane == x0) ? logf(1.0f + EPSF) : logf(EPSF);
    const float uniflp = logf(1.0f / (float)K_);

    float control = mix_logits(x0lp, uniflp, tn);
    float logit = mix_logits(log_net, control, cr);

    float m2 = wave_max64(logit);
    float e = expf(logit - m2);
    float s2 = wave_sum64(e);
    return e / s2;
}

// Phase 1: one wave per (t_idx, x0) combo; 256 combos total.
// Writes per-combo tables: m_st[k], prob_stay[j], prob_move[j], 1/denom[j].
__global__ __launch_bounds__(256) void precomp_kernel(
        const float* __restrict__ W_emb,
        const float* __restrict__ W_t,
        const int* __restrict__ t,
        float* __restrict__ MST, float* __restrict__ A,
        float* __restrict__ PM, float* __restrict__ RD) {
    const int tid = threadIdx.x;
    const int lane = tid & 63;
    const int c = blockIdx.x * 4 + (tid >> 6);   // combo in [0, 256)
    const int t_idx = c >> 6;
    const int x0 = c & 63;
    const int tb = t[t_idx];

    const float we = W_emb[x0 * K_ + lane];
    const float u_t = get_u(lane, we, W_t, tb, x0);
    const float u_s = get_u(lane, we, W_t, tb - 1, x0);

    const float diff = fmaxf(u_s - u_t, 0.0f);
    const float D = wave_sum64(diff);
    const float S = D / (D + EPSF);              // sum_k m_st
    const float a = fminf(u_s, u_t) / (u_t + EPSF);   // prob_stay as fn of j=lane
    const float pm = fmaxf(u_t - u_s, 0.0f) / (u_t + EPSF); // prob_move(j)

    const int o = c * K_ + lane;
    MST[o] = diff / (D + EPSF);
    A[o] = a;
    PM[o] = pm;
    RD[o] = 1.0f / (a + pm * S + EPSF);
}

// Phase 2: one lane per output element.
__global__ __launch_bounds__(256) void out_kernel(
        const int* __restrict__ x_0, const int* __restrict__ x_t,
        const float* __restrict__ MST, const float* __restrict__ A,
        const float* __restrict__ PM, const float* __restrict__ RD,
        float* __restrict__ out) {
    const int tid = threadIdx.x;
    const int lane = tid & 63;
    const int p = blockIdx.x * 4 + (tid >> 6);   // position in [0, B*L)
    const int b = p >> 11;                        // L_ = 2048
    const int x0 = x_0[p];
    const int xt = x_t[p];
    const int c = b * K_ + x0;

    const float mst = MST[c * K_ + lane];
    const float a  = A[c * K_ + xt];              // wave-uniform broadcast
    const float pm = PM[c * K_ + xt];
    const float rd = RD[c * K_ + xt];

    const float q = ((lane == xt) ? a : 0.0f) + pm * mst;
    out[p * K_ + lane] = logf(fmaf(q, rd, EPSF));
}

// Fallback (ws too small): original fused kernel, one wave per position.
__global__ __launch_bounds__(256) void fldd_kernel(
        const float* __restrict__ W_emb,
        const float* __restrict__ W_t,
        const int* __restrict__ x_0,
        const int* __restrict__ x_t,
        const int* __restrict__ t,
        float* __restrict__ out) {
    const int tid = threadIdx.x;
    const int lane = tid & 63;
    const int p = blockIdx.x * 4 + (tid >> 6);
    if (p >= B_ * L_) return;
    const int b = p >> 11;

    const int x0 = x_0[p];
    const int xt = x_t[p];
    const int tb = t[b];

    const float we = W_emb[x0 * K_ + lane];
    const float u_t = get_u(lane, we, W_t, tb, x0);
    const float u_s = get_u(lane, we, W_t, tb - 1, x0);

    const float diff = fmaxf(u_s - u_t, 0.0f);
    const float D = wave_sum64(diff);
    const float m_st = diff / (D + EPSF);
    const float S = D / (D + EPSF);

    const float usj = __shfl(u_s, xt, 64);
    const float utj = __shfl(u_t, xt, 64);
    const float prob_stay = fminf(usj, utj) / (utj + EPSF);
    const float prob_move = fmaxf(utj - usj, 0.0f) / (utj + EPSF);

    const float q = ((lane == xt) ? prob_stay : 0.0f) + prob_move * m_st;
    const float denom = prob_stay + prob_move * S + EPSF;
    out[p * K_ + lane] = logf(q / denom + EPSF);
}

extern "C" void kernel_launch(void* const* d_in, const int* in_sizes, int n_in,
                              void* d_out, int out_size, void* d_ws, size_t ws_size,
                              hipStream_t stream) {
    const float* W_emb = (const float*)d_in[0];
    const float* W_t   = (const float*)d_in[1];
    const int*   x_0   = (const int*)d_in[2];
    const int*   x_t   = (const int*)d_in[3];
    const int*   t     = (const int*)d_in[4];
    float* out = (float*)d_out;

    const size_t tab = (size_t)B_ * K_ * K_;      // 16384 floats per table
    if (ws_size >= 4 * tab * sizeof(float)) {
        float* MST = (float*)d_ws;
        float* A   = MST + tab;
        float* PM  = A + tab;
        float* RD  = PM + tab;
        precomp_kernel<<<64, 256, 0, stream>>>(W_emb, W_t, t, MST, A, PM, RD);
        out_kernel<<<B_ * L_ / 4, 256, 0, stream>>>(x_0, x_t, MST, A, PM, RD, out);
    } else {
        fldd_kernel<<<B_ * L_ / 4, 256, 0, stream>>>(W_emb, W_t, x_0, x_t, t, out);
    }
}